// Round 3
// baseline (122.173 us; speedup 1.0000x reference)
//
#include <hip/hip_runtime.h>

#define NDIM 28
#define SPAT 784            // 28*28
#define STRIPS 196          // float4 strips per plane
#define NB 256
#define CIN 256
#define COUT 256
#define XSC 36              // LDS halo'd plane row stride (floats): 36%8=4 -> bank rotation, 144B 16B-aligned
#define WLD 12              // LDS weight row stride (floats): 48B, 16B-aligned

// One block per batch b. 1024 threads = 4 groups x 256.
// Phase A: group g sums x[b, 64g..64g+63, :, :]  -> pb[g][strip]
//          (threads t<256 also stage w[t,0,:,:] -> wl)
// Combine: threads 0..195 fold 4 partials -> halo'd xs[30][36] in LDS
// Phase B: group g computes out[b, 64g..64g+63, :, :]; window in regs, reused 64x.
__global__ __launch_bounds__(1024) void k_fused(const float* __restrict__ x,
                                                const float* __restrict__ w,
                                                float* __restrict__ out) {
    __shared__ float4 pb[4][STRIPS];        // 12.5 KB
    __shared__ float  xs[30 * XSC];         // 4.3 KB
    __shared__ float  wl[COUT * WLD];       // 12.3 KB

    const int b  = blockIdx.x;
    const int t  = threadIdx.x;
    const int g  = t >> 8;                  // 0..3
    const int sp = t & 255;                 // strip id, active if <196

    // ---- stage weights (overlaps with phase A's global reads) ----
    if (t < COUT) {
        const float* wp = w + (size_t)t * (CIN * 9);   // kernel[t, 0, :, :]
        float4 w0 = *(const float4*)(wp);              // 9216B stride: 16B-aligned
        float4 w1 = *(const float4*)(wp + 4);
        float  w2 = wp[8];
        float* dst = wl + t * WLD;
        dst[0] = w0.x; dst[1] = w0.y; dst[2] = w0.z; dst[3] = w0.w;
        dst[4] = w1.x; dst[5] = w1.y; dst[6] = w1.z; dst[7] = w1.w;
        dst[8] = w2;
    }

    // ---- phase A: partial reduction over 64 planes ----
    if (sp < STRIPS) {
        const float4* xp = (const float4*)x + ((size_t)b * CIN + g * 64) * STRIPS + sp;
        float ax = 0.f, ay = 0.f, az = 0.f, aw = 0.f;
        #pragma unroll 16
        for (int c = 0; c < 64; ++c) {
            float4 v = xp[c * STRIPS];
            ax += v.x; ay += v.y; az += v.z; aw += v.w;
        }
        pb[g][sp] = make_float4(ax, ay, az, aw);
    }
    __syncthreads();

    // ---- combine + build halo'd plane ----
    if (t < STRIPS) {
        float4 a  = pb[0][t];
        float4 v1 = pb[1][t], v2 = pb[2][t], v3 = pb[3][t];
        a.x += v1.x + v2.x + v3.x;
        a.y += v1.y + v2.y + v3.y;
        a.z += v1.z + v2.z + v3.z;
        a.w += v1.w + v2.w + v3.w;
        int i = t / 7, q = t % 7;
        *(float4*)&xs[i * XSC + q * 4] = a;
        if (q == 0)                         // col halo: cols 28,29 = cols 0,1
            *(float4*)&xs[i * XSC + 28] = a;
        if (i < 2) {                        // row halo: rows 28,29 = rows 0,1
            *(float4*)&xs[(i + 28) * XSC + q * 4] = a;
            if (q == 0)
                *(float4*)&xs[(i + 28) * XSC + 28] = a;
        }
    }
    __syncthreads();

    // ---- phase B: conv, group g covers co in [64g, 64g+64) ----
    if (sp < STRIPS) {
        int i  = sp / 7;
        int js = (sp % 7) * 4;

        float W[3][8];
        #pragma unroll
        for (int a = 0; a < 3; ++a) {
            float4 lo = *(const float4*)&xs[(i + a) * XSC + js];
            float4 hi = *(const float4*)&xs[(i + a) * XSC + js + 4];
            W[a][0] = lo.x; W[a][1] = lo.y; W[a][2] = lo.z; W[a][3] = lo.w;
            W[a][4] = hi.x; W[a][5] = hi.y; W[a][6] = hi.z; W[a][7] = hi.w;
        }

        size_t ob = ((size_t)b * COUT + (size_t)g * 64) * SPAT + i * NDIM + js;

        #pragma unroll 2
        for (int cl = 0; cl < 64; ++cl) {
            const float* fp = wl + (g * 64 + cl) * WLD;   // uniform addr -> LDS broadcast
            float o0 = 0.f, o1 = 0.f, o2 = 0.f, o3 = 0.f;
            #pragma unroll
            for (int a = 0; a < 3; ++a) {
                #pragma unroll
                for (int c = 0; c < 3; ++c) {
                    float fv = fp[8 - 3 * a - c];         // w0[co, 2-a, 2-c]
                    o0 += fv * W[a][0 + c];
                    o1 += fv * W[a][1 + c];
                    o2 += fv * W[a][2 + c];
                    o3 += fv * W[a][3 + c];
                }
            }
            float4 o = {o0, o1, o2, o3};
            *(float4*)(out + ob + (size_t)cl * SPAT) = o;
        }
    }
}

extern "C" void kernel_launch(void* const* d_in, const int* in_sizes, int n_in,
                              void* d_out, int out_size, void* d_ws, size_t ws_size,
                              hipStream_t stream) {
    const float* x = (const float*)d_in[0];       // (256,256,28,28) f32
    const float* w = (const float*)d_in[1];       // (256,256,3,3) f32
    float* out = (float*)d_out;                   // (256,256,28,28) f32
    (void)d_ws; (void)ws_size;

    k_fused<<<NB, 1024, 0, stream>>>(x, w, out);  // 256 blocks = 1 per CU
}

// Round 5
// 78.630 us; speedup vs baseline: 1.5538x; 1.5538x over previous
//
#include <hip/hip_runtime.h>

#define NDIM 28
#define SPAT 784            // 28*28
#define STRIPS 196          // float4 strips per plane
#define NB 256
#define CIN 256
#define COUT 256
#define SCH 8               // Cin split factor
#define CPC (CIN / SCH)     // 32 planes per chunk
#define XSC 36              // LDS halo'd plane row stride (floats)

typedef float f4v __attribute__((ext_vector_type(4)));   // native vec for nontemporal builtin

// Kernel 1 (IDENTICAL to R2): partial sums over Cin chunks -> pbuf[b][chunk][196] float4
__global__ __launch_bounds__(256) void k_sum(const float* __restrict__ x,
                                             float* __restrict__ pbuf) {
    int tid = blockIdx.x * 256 + threadIdx.x;   // 1568*256 = 256*8*196
    int s  = tid % STRIPS;
    int bc = tid / STRIPS;
    int chunk = bc & 7;

    const float4* xp = (const float4*)x
        + ((size_t)(bc >> 3) * CIN + (size_t)chunk * CPC) * STRIPS + s;
    float ax = 0.f, ay = 0.f, az = 0.f, aw = 0.f;
    #pragma unroll 16
    for (int c = 0; c < CPC; ++c) {
        float4 v = xp[c * STRIPS];
        ax += v.x; ay += v.y; az += v.z; aw += v.w;
    }
    ((float4*)pbuf)[(size_t)bc * STRIPS + s] = make_float4(ax, ay, az, aw);
}

// Kernel 2: combine partials (L2-resident) -> LDS halo'd plane, then conv
// 32 co per block, nontemporal float4 stores.
__global__ __launch_bounds__(256) void k_conv(const float* __restrict__ pbuf,
                                              const float* __restrict__ w,
                                              float* __restrict__ out) {
    __shared__ float xs[30 * XSC];

    int b  = blockIdx.x >> 3;   // 0..255
    int cg = blockIdx.x & 7;    // co group: 32 co each
    int t  = threadIdx.x;

    if (t < STRIPS) {
        const float4* pp = (const float4*)pbuf + (size_t)b * SCH * STRIPS + t;
        float4 a = pp[0];
        #pragma unroll
        for (int c = 1; c < SCH; ++c) {
            float4 v = pp[c * STRIPS];
            a.x += v.x; a.y += v.y; a.z += v.z; a.w += v.w;
        }
        int i = t / 7, q = t % 7;
        *(float4*)&xs[i * XSC + q * 4] = a;
        if (q == 0)                          // col halo: cols 28,29 = cols 0,1
            *(float4*)&xs[i * XSC + 28] = a;
        if (i < 2) {                         // row halo: rows 28,29 = rows 0,1
            *(float4*)&xs[(i + 28) * XSC + q * 4] = a;
            if (q == 0)
                *(float4*)&xs[(i + 28) * XSC + 28] = a;
        }
    }
    __syncthreads();

    if (t >= STRIPS) return;
    int i  = t / 7;
    int js = (t % 7) * 4;

    float W[3][8];
    #pragma unroll
    for (int a = 0; a < 3; ++a) {
        float4 lo = *(const float4*)&xs[(i + a) * XSC + js];
        float4 hi = *(const float4*)&xs[(i + a) * XSC + js + 4];
        W[a][0] = lo.x; W[a][1] = lo.y; W[a][2] = lo.z; W[a][3] = lo.w;
        W[a][4] = hi.x; W[a][5] = hi.y; W[a][6] = hi.z; W[a][7] = hi.w;
    }

    size_t ob = ((size_t)b * COUT + (size_t)cg * 32) * SPAT + i * NDIM + js;

    #pragma unroll 4
    for (int cl = 0; cl < 32; ++cl) {
        const float* wp = w + (size_t)(cg * 32 + cl) * (CIN * 9);  // kernel[co,0,:,:] (block-uniform -> scalar loads)
        float o0 = 0.f, o1 = 0.f, o2 = 0.f, o3 = 0.f;
        #pragma unroll
        for (int a = 0; a < 3; ++a) {
            #pragma unroll
            for (int c = 0; c < 3; ++c) {
                float fv = wp[8 - 3 * a - c];   // w0[co, 2-a, 2-c]
                o0 += fv * W[a][0 + c];
                o1 += fv * W[a][1 + c];
                o2 += fv * W[a][2 + c];
                o3 += fv * W[a][3 + c];
            }
        }
        f4v o = {o0, o1, o2, o3};
        __builtin_nontemporal_store(o, (f4v*)(out + ob + (size_t)cl * SPAT));
    }
}

extern "C" void kernel_launch(void* const* d_in, const int* in_sizes, int n_in,
                              void* d_out, int out_size, void* d_ws, size_t ws_size,
                              hipStream_t stream) {
    const float* x = (const float*)d_in[0];       // (256,256,28,28) f32
    const float* w = (const float*)d_in[1];       // (256,256,3,3) f32
    float* out = (float*)d_out;                   // (256,256,28,28) f32
    float* pbuf = (float*)d_ws;                   // 256*8*784 f32 = 6.4 MB

    k_sum<<<NB * SCH * STRIPS / 256, 256, 0, stream>>>(x, pbuf);   // 1568 blocks
    k_conv<<<NB * SCH, 256, 0, stream>>>(pbuf, w, out);            // 2048 blocks
}

// Round 6
// 77.309 us; speedup vs baseline: 1.5803x; 1.0171x over previous
//
#include <hip/hip_runtime.h>

#define NDIM 28
#define SPAT 784            // 28*28
#define STRIPS 196          // float4 strips per plane
#define NB 256
#define CIN 256
#define COUT 256
#define SCH 4               // Cin split factor
#define CPC (CIN / SCH)     // 64 planes per chunk
#define XSC 36              // LDS halo'd plane row stride (floats)

typedef float f4v __attribute__((ext_vector_type(4)));

// Kernel 1: block = (b, chunk). Grid 1024 = exactly 4 blocks/CU, zero tail.
// Thread t (<196) sums 64 planes of strip t -> pbuf[b][chunk][t].
// Every wave load = 64 lanes x 16B contiguous within one plane.
__global__ __launch_bounds__(256) void k_sum(const float* __restrict__ x,
                                             float* __restrict__ pbuf) {
    int bid = blockIdx.x;          // 0..1023
    int b     = bid >> 2;
    int chunk = bid & 3;
    int t = threadIdx.x;
    if (t >= STRIPS) return;

    const float4* xp = (const float4*)x
        + ((size_t)b * CIN + (size_t)chunk * CPC) * STRIPS + t;
    float ax = 0.f, ay = 0.f, az = 0.f, aw = 0.f;
    #pragma unroll 16
    for (int c = 0; c < CPC; ++c) {
        float4 v = xp[c * STRIPS];
        ax += v.x; ay += v.y; az += v.z; aw += v.w;
    }
    ((float4*)pbuf)[((size_t)b * SCH + chunk) * STRIPS + t] = make_float4(ax, ay, az, aw);
}

// Kernel 2: block = (b, cg of 64 co). Grid 1024 = 4 blocks/CU, zero tail.
// Fold 4 partials -> halo'd LDS plane -> 64 co of conv, nontemporal stores.
__global__ __launch_bounds__(256) void k_conv(const float* __restrict__ pbuf,
                                              const float* __restrict__ w,
                                              float* __restrict__ out) {
    __shared__ float xs[30 * XSC];

    int bid = blockIdx.x;
    int b  = bid >> 2;
    int cg = bid & 3;           // co group: 64 co each
    int t  = threadIdx.x;

    if (t < STRIPS) {
        const float4* pp = (const float4*)pbuf + (size_t)b * SCH * STRIPS + t;
        float4 a = pp[0];
        #pragma unroll
        for (int c = 1; c < SCH; ++c) {
            float4 v = pp[c * STRIPS];
            a.x += v.x; a.y += v.y; a.z += v.z; a.w += v.w;
        }
        int i = t / 7, q = t % 7;
        *(float4*)&xs[i * XSC + q * 4] = a;
        if (q == 0)                          // col halo: cols 28,29 = cols 0,1
            *(float4*)&xs[i * XSC + 28] = a;
        if (i < 2) {                         // row halo: rows 28,29 = rows 0,1
            *(float4*)&xs[(i + 28) * XSC + q * 4] = a;
            if (q == 0)
                *(float4*)&xs[(i + 28) * XSC + 28] = a;
        }
    }
    __syncthreads();

    if (t >= STRIPS) return;
    int i  = t / 7;
    int js = (t % 7) * 4;

    float W[3][8];
    #pragma unroll
    for (int a = 0; a < 3; ++a) {
        float4 lo = *(const float4*)&xs[(i + a) * XSC + js];
        float4 hi = *(const float4*)&xs[(i + a) * XSC + js + 4];
        W[a][0] = lo.x; W[a][1] = lo.y; W[a][2] = lo.z; W[a][3] = lo.w;
        W[a][4] = hi.x; W[a][5] = hi.y; W[a][6] = hi.z; W[a][7] = hi.w;
    }

    size_t ob = ((size_t)b * COUT + (size_t)cg * 64) * SPAT + i * NDIM + js;

    #pragma unroll 4
    for (int cl = 0; cl < 64; ++cl) {
        const float* wp = w + (size_t)(cg * 64 + cl) * (CIN * 9);  // kernel[co,0,:,:], block-uniform
        float o0 = 0.f, o1 = 0.f, o2 = 0.f, o3 = 0.f;
        #pragma unroll
        for (int a = 0; a < 3; ++a) {
            #pragma unroll
            for (int c = 0; c < 3; ++c) {
                float fv = wp[8 - 3 * a - c];   // w0[co, 2-a, 2-c]
                o0 += fv * W[a][0 + c];
                o1 += fv * W[a][1 + c];
                o2 += fv * W[a][2 + c];
                o3 += fv * W[a][3 + c];
            }
        }
        f4v o = {o0, o1, o2, o3};
        __builtin_nontemporal_store(o, (f4v*)(out + ob + (size_t)cl * SPAT));
    }
}

extern "C" void kernel_launch(void* const* d_in, const int* in_sizes, int n_in,
                              void* d_out, int out_size, void* d_ws, size_t ws_size,
                              hipStream_t stream) {
    const float* x = (const float*)d_in[0];       // (256,256,28,28) f32
    const float* w = (const float*)d_in[1];       // (256,256,3,3) f32
    float* out = (float*)d_out;                   // (256,256,28,28) f32
    float* pbuf = (float*)d_ws;                   // 256*4*784 f32 = 3.2 MB

    k_sum<<<NB * SCH, 256, 0, stream>>>(x, pbuf);    // 1024 blocks, 4/CU exact
    k_conv<<<NB * SCH, 256, 0, stream>>>(pbuf, w, out); // 1024 blocks, 4/CU exact
}